// Round 1
// baseline (78.253 us; speedup 1.0000x reference)
//
#include <hip/hip_runtime.h>

// out[b,h] = sum_s emb[b,s,h] * mask[b,s]
// mask per reference _decay_mask: group-decay weights when L >= G and t < L, else 1.0
#define S_LEN 200
#define H_DIM 128   // 32 float4 per row

__global__ __launch_bounds__(256) void tse_pool_kernel(
    const float* __restrict__ emb,    // [B, S, H] f32
    const int*   __restrict__ lengths,// [B] i32
    const int*   __restrict__ gnum,   // [1] i32
    float*       __restrict__ out,    // [B, H] f32
    int B)
{
    __shared__ float  smask[S_LEN];
    __shared__ float4 sred[8][32];

    const int b   = blockIdx.x;
    const int tid = threadIdx.x;
    if (b >= B) return;

    const int L = lengths[b];
    const int G = gnum[0];

    // ---- build mask[s] in LDS (faithful to _decay_mask) ----
    if (tid < S_LEN) {
        const int t = tid;
        float m = 1.0f;
        if (L >= G && t < L) {
            const int gs = max(L / G, 1);
            const int g  = min(t / gs, G - 1);
            const int group_end = (g == G - 1) ? L : (g + 1) * gs;
            const float ei = (float)(group_end - t - 1);
            const float eg = (float)(G - 1 - g);
            m = powf(0.8f, ei) * powf(0.6f, eg);
        }
        smask[t] = m;
    }
    __syncthreads();

    // ---- weighted sum-pool: 8 s-rows x 32 lanes of float4 ----
    const int sRow = tid >> 5;   // 0..7
    const int quad = tid & 31;   // 0..31  (float4 column)
    const float4* __restrict__ emb4 =
        reinterpret_cast<const float4*>(emb) + (size_t)b * S_LEN * 32;

    float4 acc = make_float4(0.f, 0.f, 0.f, 0.f);
    #pragma unroll 5
    for (int s = sRow; s < S_LEN; s += 8) {
        const float4 v = emb4[(size_t)s * 32 + quad];
        const float  m = smask[s];
        acc.x = fmaf(v.x, m, acc.x);
        acc.y = fmaf(v.y, m, acc.y);
        acc.z = fmaf(v.z, m, acc.z);
        acc.w = fmaf(v.w, m, acc.w);
    }

    sred[sRow][quad] = acc;
    __syncthreads();
    if (sRow < 4) {
        const float4 o = sred[sRow + 4][quad];
        acc.x += o.x; acc.y += o.y; acc.z += o.z; acc.w += o.w;
        sred[sRow][quad] = acc;
    }
    __syncthreads();
    if (sRow < 2) {
        const float4 o = sred[sRow + 2][quad];
        acc.x += o.x; acc.y += o.y; acc.z += o.z; acc.w += o.w;
        sred[sRow][quad] = acc;
    }
    __syncthreads();
    if (sRow == 0) {
        const float4 o = sred[1][quad];
        acc.x += o.x; acc.y += o.y; acc.z += o.z; acc.w += o.w;
        reinterpret_cast<float4*>(out)[(size_t)b * 32 + quad] = acc;
    }
}

extern "C" void kernel_launch(void* const* d_in, const int* in_sizes, int n_in,
                              void* d_out, int out_size, void* d_ws, size_t ws_size,
                              hipStream_t stream) {
    const float* emb     = (const float*)d_in[0];
    const int*   lengths = (const int*)d_in[1];
    const int*   gnum    = (const int*)d_in[2];
    float*       out     = (float*)d_out;
    const int B = in_sizes[1];   // lengths has B elements

    tse_pool_kernel<<<B, 256, 0, stream>>>(emb, lengths, gnum, out, B);
}

// Round 3
// 67.358 us; speedup vs baseline: 1.1617x; 1.1617x over previous
//
#include <hip/hip_runtime.h>

// out[b,h] = sum_s emb[b,s,h] * mask[b,s]
// mask per reference _decay_mask: group-decay weights when L >= G and t < L, else 1.0
#define S_LEN 200
#define H_DIM 128   // 32 float4 per row; S*H/4 = 6400 float4 per batch row

typedef float f32x4 __attribute__((ext_vector_type(4)));

__global__ __launch_bounds__(256) void tse_pool_kernel(
    const float* __restrict__ emb,    // [B, S, H] f32
    const int*   __restrict__ lengths,// [B] i32
    const int*   __restrict__ gnum,   // [1] i32
    float*       __restrict__ out,    // [B, H] f32
    int B)
{
    __shared__ float  smask[S_LEN];
    __shared__ f32x4  sred[8][32];

    const int b   = blockIdx.x;
    const int tid = threadIdx.x;

    const int L = lengths[b];
    const int G = gnum[0];

    // ---- build mask[s] in LDS (faithful to _decay_mask) ----
    if (tid < S_LEN) {
        const int t = tid;
        float m = 1.0f;
        if (L >= G && t < L) {
            const int gs = max(L / G, 1);
            const int g  = min(t / gs, G - 1);
            const int group_end = (g == G - 1) ? L : (g + 1) * gs;
            const float ei = (float)(group_end - t - 1);
            const float eg = (float)(G - 1 - g);
            m = powf(0.8f, ei) * powf(0.6f, eg);
        }
        smask[t] = m;
    }
    __syncthreads();

    // ---- weighted sum-pool, flat-indexed: float4 idx tid + 256*j, j=0..24 ----
    // flat float4 index i covers s = i >> 5; with i = tid + 256j, s = sRow + 8j.
    const int sRow = tid >> 5;   // 0..7
    const int quad = tid & 31;   // 0..31
    const f32x4* __restrict__ emb4 =
        reinterpret_cast<const f32x4*>(emb) + (size_t)b * (S_LEN * 32);

    f32x4 acc0 = (f32x4)(0.f);
    f32x4 acc1 = (f32x4)(0.f);

    #pragma unroll
    for (int j = 0; j < 12; ++j) {
        const int i0 = tid + 512 * j;        // s = sRow + 16j
        const int i1 = i0 + 256;             // s = sRow + 16j + 8
        const f32x4 v0 = __builtin_nontemporal_load(emb4 + i0);
        const f32x4 v1 = __builtin_nontemporal_load(emb4 + i1);
        const float m0 = smask[sRow + 16 * j];
        const float m1 = smask[sRow + 16 * j + 8];
        acc0 += v0 * m0;
        acc1 += v1 * m1;
    }
    {   // leftover j = 24: flat idx tid + 6144, s = sRow + 192
        const f32x4 v = __builtin_nontemporal_load(emb4 + tid + 6144);
        const float m = smask[sRow + 192];
        acc0 += v * m;
    }
    f32x4 acc = acc0 + acc1;

    // ---- reduce across the 8 s-rows ----
    sred[sRow][quad] = acc;
    __syncthreads();
    if (sRow < 4) {
        acc += sred[sRow + 4][quad];
        sred[sRow][quad] = acc;
    }
    __syncthreads();
    if (sRow < 2) {
        acc += sred[sRow + 2][quad];
        sred[sRow][quad] = acc;
    }
    __syncthreads();
    if (sRow == 0) {
        acc += sred[1][quad];
        reinterpret_cast<f32x4*>(out)[(size_t)b * 32 + quad] = acc;
    }
}

extern "C" void kernel_launch(void* const* d_in, const int* in_sizes, int n_in,
                              void* d_out, int out_size, void* d_ws, size_t ws_size,
                              hipStream_t stream) {
    const float* emb     = (const float*)d_in[0];
    const int*   lengths = (const int*)d_in[1];
    const int*   gnum    = (const int*)d_in[2];
    float*       out     = (float*)d_out;
    const int B = in_sizes[1];   // lengths has B elements

    tse_pool_kernel<<<B, 256, 0, stream>>>(emb, lengths, gnum, out, B);
}